// Round 6
// baseline (210.721 us; speedup 1.0000x reference)
//
#include <hip/hip_runtime.h>

#define NT 8
#define NY 32
#define NX 32
#define NN 1024  // NY*NX

// Stencil coefficients of M = I + A for one node. c[(ry+1)*3+(rx+1)] is the
// coefficient toward target offset (ry,rx); zeroed when the TARGET node falls
// off-grid (matches reference `valid` masking on the column node).
__device__ __forceinline__ void node_coefs(const float* __restrict__ kap,
                                           const float* __restrict__ m,
                                           const float* __restrict__ H,
                                           const float* __restrict__ tau,
                                           int b, int node, int tc,
                                           int iy, int ix,
                                           float* c /*[9]*/, float& w) {
    const int base = node * NT + tc;                 // [.., node, t] layout, last dim NT
    const float kp  = kap[(b * NN) * NT + base];
    const float m1  = m[((b * 2 + 0) * NN) * NT + base];
    const float m2  = m[((b * 2 + 1) * NN) * NT + base];
    const float h11 = H[((b * 4 + 0) * NN) * NT + base];
    const float h12 = H[((b * 4 + 1) * NN) * NT + base];
    const float h22 = H[((b * 4 + 3) * NN) * NT + base];
    const float tv  = tau[(b * NN) * NT + base];
    w = 1.0f / (tv * tv);

    const float cxy = 0.5f * h12;
    const bool ym = iy > 0, yp = iy < NY - 1;
    const bool xm = ix > 0, xp = ix < NX - 1;

    c[4] = 1.0f + kp * kp + 2.0f * h11 + 2.0f * h22;
    c[0] = (ym && xm) ? -cxy               : 0.0f;
    c[1] =  ym        ? (-h22 - 0.5f * m2) : 0.0f;
    c[2] = (ym && xp) ?  cxy               : 0.0f;
    c[3] =  xm        ? (-h11 - 0.5f * m1) : 0.0f;
    c[5] =  xp        ? (-h11 + 0.5f * m1) : 0.0f;
    c[6] = (yp && xm) ?  cxy               : 0.0f;
    c[7] =  yp        ? (-h22 + 0.5f * m2) : 0.0f;
    c[8] = (yp && xp) ? -cxy               : 0.0f;
}

// One block per (b, t, jy): computes coefs for grid-rows jy-1..jy+1 at time t,
// then streams THREE contiguous 128 KB slabs (32 output rows each):
//   D[t]     rows jy*32..+31
//   lower[t] rows jy*32..+31  (zeros when t==0)
//   upper[t-1] rows jy*32..+31 for t>=1; the t==0 block writes upper[7] zeros.
__global__ __launch_bounds__(256) void slab_kernel(const float* __restrict__ kap,
                                                   const float* __restrict__ m,
                                                   const float* __restrict__ H,
                                                   const float* __restrict__ tau,
                                                   float* __restrict__ out) {
    __shared__ float sc[96][9];     // coefs of nodes (jy-1+r, c), r=0..2, c=0..31
    __shared__ float sw[96];        // w_t at those nodes (0 if off-grid)
    __shared__ float valsD[32][25]; // 5x5 D-window per node jx of grid-row jy
    __shared__ float valsU[32][9];  // -w_t[j] * M_t[j, j+off] per node jx

    const int blk = blockIdx.x;
    const int jy = blk & 31;
    const int t  = (blk >> 5) & 7;
    const int b  = blk >> 8;
    const int tid = threadIdx.x;

    // phase 0: coefficient strip
    if (tid < 96) {
        const int r = tid >> 5;        // 0..2  -> grid-row jy-1+r
        const int c = tid & 31;
        const int iy = jy - 1 + r;
        float cf[9];
        float w = 0.0f;
        if (iy >= 0 && iy < NY) {
            node_coefs(kap, m, H, tau, b, iy * NX + c, t, iy, c, cf, w);
        } else {
            #pragma unroll
            for (int q = 0; q < 9; ++q) cf[q] = 0.0f;
        }
        #pragma unroll
        for (int q = 0; q < 9; ++q) sc[tid][q] = cf[q];
        sw[tid] = w;
    }
    __syncthreads();

    // phase 1a: D windows (32 nodes x 25 entries)
    for (int e = tid; e < 32 * 25; e += 256) {
        const int jx = e / 25, widx = e % 25;
        const int dy = widx / 5 - 2, dx = widx % 5 - 2;
        float acc = 0.0f;
        #pragma unroll
        for (int d = 0; d < 9; ++d) {          // intermediate rows i = j + (ey,ex)
            const int ey = d / 3 - 1, ex = d % 3 - 1;
            const int r2y = dy - ey, r2x = dx - ex;
            if (r2y < -1 || r2y > 1 || r2x < -1 || r2x > 1) continue;
            const int col = jx + ex;
            if ((unsigned)col >= 32u) continue;
            const int i = (ey + 1) * 32 + col;
            acc += sw[i] * sc[i][8 - d] * sc[i][(r2y + 1) * 3 + (r2x + 1)];
        }
        if (widx == 12 && t < NT - 1) {        // diagonal: + w_{t+1}[j]
            const float tv = tau[((size_t)b * NN + jy * NX + jx) * NT + (t + 1)];
            acc += 1.0f / (tv * tv);
        }
        valsD[jx][widx] = acc;
    }
    // phase 1b: U values (32 nodes x 9 offsets)
    for (int e = tid; e < 32 * 9; e += 256) {
        const int jx = e / 9, off = e % 9;
        valsU[jx][off] = -sw[32 + jx] * sc[32 + jx][off];
    }
    __syncthreads();

    // phase 2: stream three contiguous slabs
    const int cy  = tid >> 3;              // column y of this thread's quad
    const int cx0 = (tid & 7) * 4;         // first column x
    const int ddy = cy - jy;
    float4* const outq = (float4*)out;
    const size_t rowbase = ((size_t)jy << 13) + tid;   // (jy*32 rows)*256 quads + tid

    // --- D[t] slab ---
    {
        float4* p = outq + (((size_t)(b * 3 + 0) * NT + t) << 18) + rowbase;
        const bool act = (ddy >= -2 && ddy <= 2);
        const float* wrow = &valsD[0][(ddy + 2) * 5 + 2];
        #pragma unroll 4
        for (int jx = 0; jx < 32; ++jx) {
            float4 v = make_float4(0.f, 0.f, 0.f, 0.f);
            if (act) {
                float* vp = &v.x;
                #pragma unroll
                for (int qq = 0; qq < 4; ++qq) {
                    const int ddx = cx0 + qq - jx;
                    if (ddx >= -2 && ddx <= 2) vp[qq] = wrow[jx * 25 + ddx];
                }
            }
            p[(size_t)jx << 8] = v;
        }
    }

    // --- lower[t] slab (zeros when t==0) ---
    {
        float4* p = outq + (((size_t)(b * 3 + 1) * NT + t) << 18) + rowbase;
        const bool act = (t > 0) && (ddy >= -1 && ddy <= 1);
        float Lv[12];                       // hoisted: per qq, 3 candidate values
        if (act) {
            #pragma unroll
            for (int qq = 0; qq < 4; ++qq) {
                const int k = (ddy + 1) * 32 + cx0 + qq;   // column node in strip
                const float wk = sw[k];
                #pragma unroll
                for (int xi = 0; xi < 3; ++xi)             // xi = ddx+1
                    Lv[qq * 3 + xi] = -wk * sc[k][8 - ((ddy + 1) * 3 + xi)];
            }
        }
        #pragma unroll 4
        for (int jx = 0; jx < 32; ++jx) {
            float4 v = make_float4(0.f, 0.f, 0.f, 0.f);
            if (act) {
                float* vp = &v.x;
                #pragma unroll
                for (int qq = 0; qq < 4; ++qq) {
                    const int ddx = cx0 + qq - jx;
                    if (ddx >= -1 && ddx <= 1) vp[qq] = Lv[qq * 3 + ddx + 1];
                }
            }
            p[(size_t)jx << 8] = v;
        }
    }

    // --- upper slab: t>=1 -> upper[t-1]; t==0 -> upper[NT-1] zeros ---
    {
        const int ut = (t >= 1) ? (t - 1) : (NT - 1);
        float4* p = outq + (((size_t)(b * 3 + 2) * NT + ut) << 18) + rowbase;
        const bool act = (t >= 1) && (ddy >= -1 && ddy <= 1);
        #pragma unroll 4
        for (int jx = 0; jx < 32; ++jx) {
            float4 v = make_float4(0.f, 0.f, 0.f, 0.f);
            if (act) {
                float* vp = &v.x;
                #pragma unroll
                for (int qq = 0; qq < 4; ++qq) {
                    const int ddx = cx0 + qq - jx;
                    if (ddx >= -1 && ddx <= 1)
                        vp[qq] = valsU[jx][(ddy + 1) * 3 + ddx + 1];
                }
            }
            p[(size_t)jx << 8] = v;
        }
    }
}

extern "C" void kernel_launch(void* const* d_in, const int* in_sizes, int n_in,
                              void* d_out, int out_size, void* d_ws, size_t ws_size,
                              hipStream_t stream) {
    const float* kap = (const float*)d_in[0];  // [n_b,1,N,NT]
    const float* m   = (const float*)d_in[1];  // [n_b,2,N,NT]
    const float* H   = (const float*)d_in[2];  // [n_b,2,2,N,NT]
    const float* tau = (const float*)d_in[3];  // [n_b,1,N,NT]
    float* out = (float*)d_out;                // [n_b,3,NT,N,N]

    const int n_b = in_sizes[0] / (NN * NT);
    const int grid = n_b * NT * NY;            // one block per (b,t,grid-row)
    slab_kernel<<<grid, 256, 0, stream>>>(kap, m, H, tau, out);
}